// Round 1
// baseline (14498.735 us; speedup 1.0000x reference)
//
#include <hip/hip_runtime.h>

#define NN 512
#define DD 32
#define TT 8192

constexpr float F_OMEGA = 10.0f;
constexpr float F_ALPHA = 0.5f;
constexpr float F_DT = 1e-3f;
constexpr float F_TWO_PI = 6.28318530717958647692f;
constexpr float F_INV_TWO_PI = 0.15915494309189533577f;

// Barrier that waits only LDS (lgkmcnt), NOT vmcnt: keeps prefetch loads and
// output stores in flight across the per-step sync (avoids the m97-style
// vmcnt(0) drain that __syncthreads() would insert).
__device__ __forceinline__ void barrier_lgkm() {
    asm volatile("s_waitcnt lgkmcnt(0)\n\ts_barrier" ::: "memory");
}

__device__ __forceinline__ void do_step(
    int t,
    const float* __restrict__ Xr, const float* __restrict__ Xi,
    const float* __restrict__ Tg,
    float (&wr)[DD], float (&wi)[DD],
    float (&xr)[DD], float (&xi)[DD],      // current step's x (already loaded)
    float (&nxr)[DD], float (&nxi)[DD],    // next step's x (prefetched here)
    float tgt, float& tgt_nxt,
    float& phi, float& beta, float& lt, float& err,
    float* __restrict__ outs, float* __restrict__ betas, float* __restrict__ gammas,
    float* sP, int n, int lane, int wid)
{
    // ---- prefetch x[t+1], tgt[t+1] (clamped index; uniform, branch-free) ----
    const int tn = (t + 1 < TT) ? (t + 1) : (TT - 1);
    const float* pr = Xr + (size_t)tn * DD;
    const float* pi_ = Xi + (size_t)tn * DD;
#pragma unroll
    for (int d = 0; d < DD; ++d) { nxr[d] = pr[d]; nxi[d] = pi_[d]; }
    tgt_nxt = Tg[tn];

    // ---- time dilation ----
    const float gamma = __expf(-F_ALPHA * beta);   // exp(-0.5*beta)
    const float dtl = gamma * F_DT;
    lt += dtl;
    const float theta = fmaf(F_OMEGA, lt, phi);

    // sin/cos via HW (input in revolutions, range-reduce first)
    float rev = theta * F_INV_TWO_PI;
    rev = rev - floorf(rev);
    const float s = __builtin_amdgcn_sinf(rev);
    const float c = __builtin_amdgcn_cosf(rev);

    // ---- Z = W @ x (complex matvec row) ----
    float zr = 0.0f, zi = 0.0f;
#pragma unroll
    for (int d = 0; d < DD; ++d) {
        zr = fmaf(wr[d], xr[d], zr);
        zr = fmaf(-wi[d], xi[d], zr);
        zi = fmaf(wr[d], xi[d], zi);
        zi = fmaf(wi[d], xr[d], zi);
    }

    // Y = |Z| * relu(cos(theta - angle(Z))) == relu(zr*cos + zi*sin)
    float Y = fmaf(zr, c, zi * s);
    Y = fmaxf(Y, 0.0f);
    float v = Y * c;                                // contribution to out

    // ---- block reduction: wave shuffle, then 8 partials through LDS ----
#pragma unroll
    for (int m = 32; m >= 1; m >>= 1) v += __shfl_xor(v, m, 64);

    barrier_lgkm();                 // WAR: previous iteration's sP reads done
    if (lane == 0) sP[wid] = v;
    barrier_lgkm();
    const float out = ((sP[0] + sP[1]) + (sP[2] + sP[3])) +
                      ((sP[4] + sP[5]) + (sP[6] + sP[7]));

    // ---- scalar feedback chain (computed redundantly, identically, per thread) ----
    const float raw = fabsf(tgt - out);
    err = 0.99f * err + 0.01f * raw;
    const float rel = err / (fabsf(tgt) + 0.01f);
    const float btg = 3.5f * __expf(-5.0f * rel);
    // tau = btg>beta ? 0.5/(gamma+1e-6) : 0.03 ; a_s = 1-exp(-DT/tau), division folded away
    const float expo = (btg > beta) ? (-2.0f * F_DT * (gamma + 1e-6f))
                                    : (-F_DT / 0.03f);
    const float a_s = 1.0f - __expf(expo);
    float bnew = beta + a_s * (btg - beta);
    bnew = fminf(fmaxf(bnew, 0.005f), 5.0f);

    // ---- Hebbian growth / viscous decay: W = W*(1 - dt*bnew*Y^2) + (0.05*Y*dt)*x ----
    const float g = 0.05f * Y * dtl;
    const float k = bnew * (Y * Y) * dtl;
    const float m1 = 1.0f - k;
#pragma unroll
    for (int d = 0; d < DD; ++d) {
        wr[d] = fmaf(wr[d], m1, g * xr[d]);
        wi[d] = fmaf(wi[d], m1, g * xi[d]);
    }

    // ---- phase pull + mod 2pi ----
    phi += (2.0f / (float)NN) * (-tgt * s) * dtl;
    phi = phi - F_TWO_PI * floorf(phi * F_INV_TWO_PI);

    // ---- outputs (stores never drained by barrier_lgkm; trickle out) ----
    gammas[t * NN + n] = gamma;     // gamma from OLD beta, per reference
    betas[t * NN + n] = bnew;
    if (n == 0) outs[t] = out;
    beta = bnew;
}

__global__ __launch_bounds__(512, 2) void deerskin(
    const float* __restrict__ Xr, const float* __restrict__ Xi,
    const float* __restrict__ Tg,
    const float* __restrict__ W0r, const float* __restrict__ W0i,
    const float* __restrict__ Phi0, const float* __restrict__ Beta0,
    float* __restrict__ outs, float* __restrict__ betas, float* __restrict__ gammas)
{
    __shared__ float sP[8];
    const int n = threadIdx.x;
    const int lane = n & 63;
    const int wid = n >> 6;

    // per-neuron W row into registers (64 VGPRs)
    float wr[DD], wi[DD];
#pragma unroll
    for (int d = 0; d < DD; ++d) {
        wr[d] = W0r[n * DD + d];
        wi[d] = W0i[n * DD + d];
    }
    float phi = Phi0[n];
    float beta = Beta0[n];
    float lt = 0.0f;
    float err = 0.0f;

    // double-buffered x in registers; 2x-unrolled loop avoids buffer-swap movs
    float xa_r[DD], xa_i[DD], xb_r[DD], xb_i[DD];
    float tgtA = Tg[0], tgtB;
#pragma unroll
    for (int d = 0; d < DD; ++d) { xa_r[d] = Xr[d]; xa_i[d] = Xi[d]; }

    for (int t = 0; t < TT; t += 2) {
        do_step(t,     Xr, Xi, Tg, wr, wi, xa_r, xa_i, xb_r, xb_i, tgtA, tgtB,
                phi, beta, lt, err, outs, betas, gammas, sP, n, lane, wid);
        do_step(t + 1, Xr, Xi, Tg, wr, wi, xb_r, xb_i, xa_r, xa_i, tgtB, tgtA,
                phi, beta, lt, err, outs, betas, gammas, sP, n, lane, wid);
    }
}

extern "C" void kernel_launch(void* const* d_in, const int* in_sizes, int n_in,
                              void* d_out, int out_size, void* d_ws, size_t ws_size,
                              hipStream_t stream) {
    const float* Xr    = (const float*)d_in[0];   // [T, D]
    const float* Xi    = (const float*)d_in[1];   // [T, D]
    const float* Tg    = (const float*)d_in[2];   // [T]
    const float* W0r   = (const float*)d_in[3];   // [N, D]
    const float* W0i   = (const float*)d_in[4];   // [N, D]
    const float* Phi0  = (const float*)d_in[5];   // [N]
    const float* Beta0 = (const float*)d_in[6];   // [N]

    float* outs   = (float*)d_out;                     // [T]
    float* betas  = outs + TT;                         // [T, N]
    float* gammas = betas + (size_t)TT * NN;           // [T, N]

    deerskin<<<1, NN, 0, stream>>>(Xr, Xi, Tg, W0r, W0i, Phi0, Beta0,
                                   outs, betas, gammas);
}

// Round 3
// 13752.692 us; speedup vs baseline: 1.0542x; 1.0542x over previous
//
#include <hip/hip_runtime.h>

#define NN 512
#define DD 32
#define TT 8192

constexpr float F_OMEGA = 10.0f;
constexpr float F_ALPHA = 0.5f;
constexpr float F_DT = 1e-3f;
constexpr float F_TWO_PI = 6.28318530717958647692f;
constexpr float F_INV_TWO_PI = 0.15915494309189533577f;

// Barrier waiting LDS/SMEM only (lgkmcnt), never vmcnt: output stores and the
// LDS-touch prefetches stay in flight across the per-step sync.
__device__ __forceinline__ void barrier_lgkm() {
    asm volatile("s_waitcnt lgkmcnt(0)\n\ts_barrier" ::: "memory");
}

// Cache-warming prefetch with NO destination register: global_load_lds writes
// to LDS scratch (never read), is tracked by vmcnt (never waited on), and
// pulls the line into L1/L2 so the later wave-uniform s_load of x[t] is a
// cache hit instead of a serial ~900-cycle HBM miss. Unlike a register-dest
// touch, there is no retire-time VGPR clobber hazard.
__device__ __forceinline__ void touch_to_lds(const float* g, float* lds_scratch) {
    __builtin_amdgcn_global_load_lds(
        (const __attribute__((address_space(1))) void*)g,
        (__attribute__((address_space(3))) void*)lds_scratch, 4, 0, 0);
}

__global__ __launch_bounds__(512, 2) void deerskin(
    const float* __restrict__ Xr, const float* __restrict__ Xi,
    const float* __restrict__ Tg,
    const float* __restrict__ W0r, const float* __restrict__ W0i,
    const float* __restrict__ Phi0, const float* __restrict__ Beta0,
    float* __restrict__ outs, float* __restrict__ betas, float* __restrict__ gammas)
{
    __shared__ __align__(16) float sP[16];      // double-buffered 8 wave-partials
    __shared__ float scratch[192];              // glds landing zone (never read)
    const int n = threadIdx.x;
    const int lane = n & 63;
    const int wid = n >> 6;

    // Per-neuron W row in registers (64 VGPRs).
    float wr[DD], wi[DD];
#pragma unroll
    for (int d = 0; d < DD; ++d) {
        wr[d] = W0r[n * DD + d];
        wi[d] = W0i[n * DD + d];
    }
    float phi = Phi0[n];
    float beta = Beta0[n];
    float lt = 0.0f;
    float err = 0.0f;

    for (int t = 0; t < TT; ++t) {
        // ---- x[t]: wave-uniform -> compiler emits s_load (SGPRs, zero VGPR
        // cost). L1/L2-warm thanks to touches issued ~4 steps ago.
        const float* xr = Xr + (size_t)t * DD;
        const float* xi = Xi + (size_t)t * DD;
        float xrv[DD], xiv[DD];
#pragma unroll
        for (int d = 0; d < DD; ++d) { xrv[d] = xr[d]; xiv[d] = xi[d]; }
        const float tgt = Tg[t];

        // ---- time dilation + oscillator phase (independent of x; fills the
        // s_load latency shadow) ----
        const float gamma = __expf(-F_ALPHA * beta);
        const float dtl = gamma * F_DT;
        lt += dtl;
        const float theta = fmaf(F_OMEGA, lt, phi);
        float rev = theta * F_INV_TWO_PI;
        rev -= floorf(rev);
        const float s = __builtin_amdgcn_sinf(rev);
        const float c = __builtin_amdgcn_cosf(rev);

        // ---- Z = W @ x (exact Round-1 op order) ----
        float zr = 0.0f, zi = 0.0f;
#pragma unroll
        for (int d = 0; d < DD; ++d) {
            zr = fmaf(wr[d], xrv[d], zr);
            zr = fmaf(-wi[d], xiv[d], zr);
            zi = fmaf(wr[d], xiv[d], zi);
            zi = fmaf(wi[d], xrv[d], zi);
        }

        // Y = |Z| * relu(cos(theta - angle(Z))) == relu(zr*cos + zi*sin)
        const float Y = fmaxf(fmaf(zr, c, zi * s), 0.0f);
        float v = Y * c;

        // ---- reduce 512 -> 1: wave shuffle + LDS partials.
        // sP double-buffered on (t&1) -> single barrier per step.
#pragma unroll
        for (int m = 32; m >= 1; m >>= 1) v += __shfl_xor(v, m, 64);
        if (lane == 0) sP[((t & 1) << 3) + wid] = v;
        barrier_lgkm();

        const int sb = (t & 1) << 3;
        const float out = ((sP[sb + 0] + sP[sb + 1]) + (sP[sb + 2] + sP[sb + 3])) +
                          ((sP[sb + 4] + sP[sb + 5]) + (sP[sb + 6] + sP[sb + 7]));

        // ---- scalar feedback chain (redundant per thread, identical) ----
        const float raw = fabsf(tgt - out);
        err = 0.99f * err + 0.01f * raw;
        const float rel = err / (fabsf(tgt) + 0.01f);
        const float btg = 3.5f * __expf(-5.0f * rel);
        const float expo = (btg > beta) ? (-2.0f * F_DT * (gamma + 1e-6f))
                                        : (-F_DT / 0.03f);
        const float a_s = 1.0f - __expf(expo);
        float bnew = beta + a_s * (btg - beta);
        bnew = fminf(fmaxf(bnew, 0.005f), 5.0f);

        // ---- W = W*(1 - dt*bnew*Y^2) + (0.05*Y*dt)*x  (Round-1 order) ----
        const float g = 0.05f * Y * dtl;
        const float k = bnew * (Y * Y) * dtl;
        const float m1 = 1.0f - k;
#pragma unroll
        for (int d = 0; d < DD; ++d) {
            wr[d] = fmaf(wr[d], m1, g * xrv[d]);
            wi[d] = fmaf(wi[d], m1, g * xiv[d]);
        }

        // ---- phase pull + wrap ----
        phi += (2.0f / (float)NN) * (-tgt * s) * dtl;
        phi = phi - F_TWO_PI * floorf(phi * F_INV_TWO_PI);

        // ---- outputs (stores trickle; nothing in the loop waits vmcnt) ----
        gammas[t * NN + n] = gamma;    // gamma from OLD beta, per reference
        betas[t * NN + n] = bnew;
        if (n == 0) outs[t] = out;
        beta = bnew;

        // ---- prefetch touches for x[t+4..t+5] + tgt, wave 0 only.
        // 64 lanes x 4B = 256B per base = two X rows per touch op.
        if (wid == 0) {
            const int tn = (t + 4 < TT - 1) ? (t + 4) : (TT - 2);
            touch_to_lds(Xr + (size_t)tn * DD + lane, scratch);
            touch_to_lds(Xi + (size_t)tn * DD + lane, scratch + 64);
            const int tb = (t + 8 < TT) ? (t + 8) : (TT - 1);
            touch_to_lds(Tg + tb, scratch + 128);   // same addr all lanes, 1 line
        }
    }
}

extern "C" void kernel_launch(void* const* d_in, const int* in_sizes, int n_in,
                              void* d_out, int out_size, void* d_ws, size_t ws_size,
                              hipStream_t stream) {
    const float* Xr    = (const float*)d_in[0];   // [T, D]
    const float* Xi    = (const float*)d_in[1];   // [T, D]
    const float* Tg    = (const float*)d_in[2];   // [T]
    const float* W0r   = (const float*)d_in[3];   // [N, D]
    const float* W0i   = (const float*)d_in[4];   // [N, D]
    const float* Phi0  = (const float*)d_in[5];   // [N]
    const float* Beta0 = (const float*)d_in[6];   // [N]

    float* outs   = (float*)d_out;                // [T]
    float* betas  = outs + TT;                    // [T, N]
    float* gammas = betas + (size_t)TT * NN;      // [T, N]

    deerskin<<<1, NN, 0, stream>>>(Xr, Xi, Tg, W0r, W0i, Phi0, Beta0,
                                   outs, betas, gammas);
}

// Round 4
// 12790.260 us; speedup vs baseline: 1.1336x; 1.0752x over previous
//
#include <hip/hip_runtime.h>

#define NN 512
#define DD 32
#define DP (DD/2)
#define TT 8192

typedef float v2f __attribute__((ext_vector_type(2)));

constexpr float F_OMEGA = 10.0f;
constexpr float F_DT = 1e-3f;
constexpr float F_TWO_PI = 6.28318530717958647692f;
constexpr float F_INV_TWO_PI = 0.15915494309189533577f;

// Barrier waiting LDS/SMEM only (lgkmcnt), never vmcnt: output stores and the
// LDS-touch prefetches stay in flight across the per-step sync.
__device__ __forceinline__ void barrier_lgkm() {
    asm volatile("s_waitcnt lgkmcnt(0)\n\ts_barrier" ::: "memory");
}

// Cache-warming prefetch with NO destination register (Round-3, passing):
// global_load_lds -> LDS scratch (never read), tracked by vmcnt (never waited
// on). Pulls X lines into L1/L2 so the step's uniform loads hit cache.
__device__ __forceinline__ void touch_to_lds(const float* g, float* lds_scratch) {
    __builtin_amdgcn_global_load_lds(
        (const __attribute__((address_space(1))) void*)g,
        (__attribute__((address_space(3))) void*)lds_scratch, 4, 0, 0);
}

// One step of a DPP-based wave64 reduction: x += dpp_move(x). Masked-out
// dest rows add 0 (old=0), i.e. stay unchanged.
#define DPP_ADD(x, ctrl, rmask)                                                 \
    {                                                                           \
        int _t = __builtin_amdgcn_update_dpp(0, __float_as_int(x),              \
                                             (ctrl), (rmask), 0xf, true);       \
        (x) += __int_as_float(_t);                                              \
    }

// Full 64-lane sum via VALU DPP chain (no LDS pipe): after this, lane 63
// holds the wave total. ~6 dependent v_add_f32_dpp (~40cyc) vs ~250cyc for
// six serial ds_swizzle hops.
__device__ __forceinline__ float wave_reduce_to_lane63(float x) {
    DPP_ADD(x, 0xB1, 0xf);   // quad_perm [1,0,3,2]  : + xor1
    DPP_ADD(x, 0x4E, 0xf);   // quad_perm [2,3,0,1]  : + xor2
    DPP_ADD(x, 0x141, 0xf);  // row_half_mirror      : + xor4
    DPP_ADD(x, 0x140, 0xf);  // row_mirror           : + xor8 -> row(16) sums
    DPP_ADD(x, 0x142, 0xa);  // row_bcast15 -> rows 1,3 accumulate prev row
    DPP_ADD(x, 0x143, 0xc);  // row_bcast31 -> rows 2,3 accumulate lanes 0-31
    return x;                // lane 63 = full sum
}

__global__ __launch_bounds__(512, 2) void deerskin(
    const float* __restrict__ Xr, const float* __restrict__ Xi,
    const float* __restrict__ Tg,
    const float* __restrict__ W0r, const float* __restrict__ W0i,
    const float* __restrict__ Phi0, const float* __restrict__ Beta0,
    float* __restrict__ outs, float* __restrict__ betas, float* __restrict__ gammas)
{
    __shared__ __align__(16) float sP[16];      // double-buffered 8 wave-partials
    __shared__ float scratch[192];              // glds landing zone (never read)
    const int n = threadIdx.x;
    const int lane = n & 63;
    const int wid = n >> 6;

    // Per-neuron W row in registers as d-pair float2s (v_pk_fma operands).
    v2f wr[DP], wi[DP];
    {
        const v2f* wr0 = (const v2f*)(W0r + n * DD);
        const v2f* wi0 = (const v2f*)(W0i + n * DD);
#pragma unroll
        for (int j = 0; j < DP; ++j) { wr[j] = wr0[j]; wi[j] = wi0[j]; }
    }
    float phi = Phi0[n];
    float beta = Beta0[n];
    float lt = 0.0f;
    float err = 0.0f;

    for (int t = 0; t < TT; ++t) {
        // ---- x[t]: wave-uniform pair loads (SGPR-pair friendly; VOP3P takes
        // one scalar operand, so pk_fma consumes these directly). L2-warm.
        const v2f* xr2 = (const v2f*)(Xr + (size_t)t * DD);
        const v2f* xi2 = (const v2f*)(Xi + (size_t)t * DD);
        v2f xr[DP], xi[DP];
#pragma unroll
        for (int j = 0; j < DP; ++j) { xr[j] = xr2[j]; xi[j] = xi2[j]; }
        const float tgt = Tg[t];

        // ---- time dilation + oscillator phase (independent of x; fills the
        // load-latency shadow) ----
        const float gamma = __expf(-0.5f * beta);
        const float dtl = gamma * F_DT;
        lt += dtl;
        const float theta = fmaf(F_OMEGA, lt, phi);
        float rev = theta * F_INV_TWO_PI;
        rev -= floorf(rev);
        const float s = __builtin_amdgcn_sinf(rev);
        const float c = __builtin_amdgcn_cosf(rev);

        gammas[t * NN + n] = gamma;   // gamma from OLD beta, per reference

        // ---- Z = W @ x as 4 packed accumulator chains (v_pk_fma_f32) ----
        v2f Arr = {0.f, 0.f}, Aii = {0.f, 0.f}, Ari = {0.f, 0.f}, Air = {0.f, 0.f};
#pragma unroll
        for (int j = 0; j < DP; ++j) {
            Arr += wr[j] * xr[j];
            Aii += wi[j] * xi[j];
            Ari += wr[j] * xi[j];
            Air += wi[j] * xr[j];
        }
        const float zr = (Arr.x + Arr.y) - (Aii.x + Aii.y);
        const float zi = (Ari.x + Ari.y) + (Air.x + Air.y);

        // Y = |Z| * relu(cos(theta - angle(Z))) == relu(zr*cos + zi*sin)
        const float Y = fmaxf(fmaf(zr, c, zi * s), 0.0f);

        // ---- reduce 512 -> 1: DPP wave sum (VALU), 8 partials through LDS.
        float v = wave_reduce_to_lane63(Y * c);
        if (lane == 63) sP[((t & 1) << 3) + wid] = v;

        // ---- prefetch touches for x[t+4] + tgt, wave 0 only (vmcnt-tracked,
        // never waited on; issued before the barrier to maximize overlap).
        if (wid == 0) {
            const int tn = (t + 4 < TT - 1) ? (t + 4) : (TT - 2);
            touch_to_lds(Xr + (size_t)tn * DD + lane, scratch);
            touch_to_lds(Xi + (size_t)tn * DD + lane, scratch + 64);
            const int tb = (t + 8 < TT) ? (t + 8) : (TT - 1);
            touch_to_lds(Tg + tb, scratch + 128);
        }

        barrier_lgkm();

        const int sb = (t & 1) << 3;
        const float4* sp4 = (const float4*)(sP + sb);
        const float4 p0 = sp4[0], p1 = sp4[1];
        const float out = ((p0.x + p0.y) + (p0.z + p0.w)) +
                          ((p1.x + p1.y) + (p1.z + p1.w));

        // ---- scalar feedback chain (redundant per thread, identical) ----
        const float raw = fabsf(tgt - out);
        err = 0.99f * err + 0.01f * raw;
        const float rel = err / (fabsf(tgt) + 0.01f);
        const float btg = 3.5f * __expf(-5.0f * rel);
        const float expo = (btg > beta) ? (-2.0f * F_DT * (gamma + 1e-6f))
                                        : (-F_DT / 0.03f);
        const float a_s = 1.0f - __expf(expo);
        float bnew = beta + a_s * (btg - beta);
        bnew = fminf(fmaxf(bnew, 0.005f), 5.0f);

        // ---- W = W*(1 - dt*bnew*Y^2) + (0.05*Y*dt)*x, packed; per-element
        // op order identical to Round 3: fma(w, m1, g*x) ----
        const float g = 0.05f * Y * dtl;
        const float k = bnew * (Y * Y) * dtl;
        const float m1 = 1.0f - k;
        const v2f m1v = {m1, m1};
        const v2f gv = {g, g};
#pragma unroll
        for (int j = 0; j < DP; ++j) {
            wr[j] = wr[j] * m1v + gv * xr[j];
            wi[j] = wi[j] * m1v + gv * xi[j];
        }

        // ---- phase pull + wrap ----
        phi += (2.0f / (float)NN) * (-tgt * s) * dtl;
        phi = phi - F_TWO_PI * floorf(phi * F_INV_TWO_PI);

        // ---- outputs (stores trickle; nothing in the loop waits vmcnt) ----
        betas[t * NN + n] = bnew;
        if (n == 0) outs[t] = out;
        beta = bnew;
    }
}

extern "C" void kernel_launch(void* const* d_in, const int* in_sizes, int n_in,
                              void* d_out, int out_size, void* d_ws, size_t ws_size,
                              hipStream_t stream) {
    const float* Xr    = (const float*)d_in[0];   // [T, D]
    const float* Xi    = (const float*)d_in[1];   // [T, D]
    const float* Tg    = (const float*)d_in[2];   // [T]
    const float* W0r   = (const float*)d_in[3];   // [N, D]
    const float* W0i   = (const float*)d_in[4];   // [N, D]
    const float* Phi0  = (const float*)d_in[5];   // [N]
    const float* Beta0 = (const float*)d_in[6];   // [N]

    float* outs   = (float*)d_out;                // [T]
    float* betas  = outs + TT;                    // [T, N]
    float* gammas = betas + (size_t)TT * NN;      // [T, N]

    deerskin<<<1, NN, 0, stream>>>(Xr, Xi, Tg, W0r, W0i, Phi0, Beta0,
                                   outs, betas, gammas);
}

// Round 5
// 12568.879 us; speedup vs baseline: 1.1535x; 1.0176x over previous
//
#include <hip/hip_runtime.h>

#define NN 512
#define DD 32
#define DP (DD/2)
#define TT 8192

typedef float v2f __attribute__((ext_vector_type(2)));

constexpr float F_OMEGA = 10.0f;
constexpr float F_DT = 1e-3f;
constexpr float F_TWO_PI = 6.28318530717958647692f;
constexpr float F_INV_TWO_PI = 0.15915494309189533577f;

// Barrier waiting LDS/SMEM only (lgkmcnt), never vmcnt: output stores and the
// next-step x prefetch loads stay in flight across the per-step sync.
__device__ __forceinline__ void barrier_lgkm() {
    asm volatile("s_waitcnt lgkmcnt(0)\n\ts_barrier" ::: "memory");
}

// One step of a DPP-based wave64 reduction: x += dpp_move(x).
#define DPP_ADD(x, ctrl, rmask)                                                 \
    {                                                                           \
        int _t = __builtin_amdgcn_update_dpp(0, __float_as_int(x),              \
                                             (ctrl), (rmask), 0xf, true);       \
        (x) += __int_as_float(_t);                                              \
    }

// Full 64-lane sum via VALU DPP chain (no LDS pipe); lane 63 holds the total.
__device__ __forceinline__ float wave_reduce_to_lane63(float x) {
    DPP_ADD(x, 0xB1, 0xf);   // quad_perm [1,0,3,2]  : + xor1
    DPP_ADD(x, 0x4E, 0xf);   // quad_perm [2,3,0,1]  : + xor2
    DPP_ADD(x, 0x141, 0xf);  // row_half_mirror      : + xor4
    DPP_ADD(x, 0x140, 0xf);  // row_mirror           : + xor8
    DPP_ADD(x, 0x142, 0xa);  // row_bcast15
    DPP_ADD(x, 0x143, 0xc);  // row_bcast31
    return x;
}

__device__ __forceinline__ void do_step(
    int t,
    const float* __restrict__ Xr, const float* __restrict__ Xi,
    const float* __restrict__ Tg,
    v2f (&wr)[DP], v2f (&wi)[DP],
    v2f (&xr)[DP], v2f (&xi)[DP],        // current x (already in registers)
    v2f (&nxr)[DP], v2f (&nxi)[DP],      // next x (prefetched here)
    float tgt, float& tgt_nxt,
    float& phi, float& beta, float& lt, float& err,
    float* __restrict__ outs, float* __restrict__ betas, float* __restrict__ gammas,
    float* sP, int n, int lane, int wid)
{
    // ---- 1. prefetch x[t+1], tgt[t+1]: issued NOW, used next step (~full
    // step of slack -> latency fully hidden; nothing waits before use).
    const int tn = (t + 1 < TT) ? (t + 1) : (TT - 1);
    {
        const v2f* pr = (const v2f*)(Xr + (size_t)tn * DD);
        const v2f* pi_ = (const v2f*)(Xi + (size_t)tn * DD);
#pragma unroll
        for (int j = 0; j < DP; ++j) { nxr[j] = pr[j]; nxi[j] = pi_[j]; }
        tgt_nxt = Tg[tn];
    }

    // ---- 2. time dilation + oscillator phase (x-independent) ----
    const float gamma = __expf(-0.5f * beta);
    const float dtl = gamma * F_DT;
    lt += dtl;
    const float theta = fmaf(F_OMEGA, lt, phi);
    float rev = theta * F_INV_TWO_PI;
    rev -= floorf(rev);
    const float s = __builtin_amdgcn_sinf(rev);
    const float c = __builtin_amdgcn_cosf(rev);

    gammas[t * NN + n] = gamma;   // gamma from OLD beta, per reference

    // ---- 3. Z = W @ x, 4 packed accumulator chains (v_pk_fma_f32) ----
    v2f Arr = {0.f, 0.f}, Aii = {0.f, 0.f}, Ari = {0.f, 0.f}, Air = {0.f, 0.f};
#pragma unroll
    for (int j = 0; j < DP; ++j) {
        Arr += wr[j] * xr[j];
        Aii += wi[j] * xi[j];
        Ari += wr[j] * xi[j];
        Air += wi[j] * xr[j];
    }
    const float zr = (Arr.x + Arr.y) - (Aii.x + Aii.y);
    const float zi = (Ari.x + Ari.y) + (Air.x + Air.y);

    // Y = |Z| * relu(cos(theta - angle(Z))) == relu(zr*cos + zi*sin)
    const float Y = fmaxf(fmaf(zr, c, zi * s), 0.0f);

    // ---- 4. reduce 512 -> 1: DPP wave sum, 8 partials via LDS ----
    float v = wave_reduce_to_lane63(Y * c);
    if (lane == 63) sP[((t & 1) << 3) + wid] = v;

    // ---- 5. precompute everything NOT depending on `out` (off the
    // post-barrier critical path) ----
    const float inv_t = 1.0f / (fabsf(tgt) + 0.01f);          // exact div, off-path
    const float a_sA = 1.0f - __expf(-2.0f * F_DT * (gamma + 1e-6f));
    const float a_sB = 1.0f - __expf(-F_DT / 0.03f);
    const float yy = Y * Y;
    const float g = 0.05f * Y * dtl;
    // phi update is out-independent: do it now (identical FP ops, reordered)
    phi += (2.0f / (float)NN) * (-tgt * s) * dtl;
    phi = phi - F_TWO_PI * floorf(phi * F_INV_TWO_PI);

    barrier_lgkm();

    // ---- 6. out + scalar feedback (short chain: one exp, no div) ----
    const float4* sp4 = (const float4*)(sP + ((t & 1) << 3));
    const float4 p0 = sp4[0], p1 = sp4[1];
    const float out = ((p0.x + p0.y) + (p0.z + p0.w)) +
                      ((p1.x + p1.y) + (p1.z + p1.w));

    const float raw = fabsf(tgt - out);
    err = 0.99f * err + 0.01f * raw;
    const float rel = err * inv_t;
    const float btg = 3.5f * __expf(-5.0f * rel);
    const float a_s = (btg > beta) ? a_sA : a_sB;
    float bnew = beta + a_s * (btg - beta);
    bnew = fminf(fmaxf(bnew, 0.005f), 5.0f);

    // ---- 7. W = W*(1 - (bnew*yy)*dtl) + g*x  (packed, R4 FP order) ----
    const float k = (bnew * yy) * dtl;
    const float m1 = 1.0f - k;
    const v2f m1v = {m1, m1};
    const v2f gv = {g, g};
#pragma unroll
    for (int j = 0; j < DP; ++j) {
        wr[j] = wr[j] * m1v + gv * xr[j];
        wi[j] = wi[j] * m1v + gv * xi[j];
    }

    // ---- 8. outputs (stores trickle; nothing in the loop waits vmcnt) ----
    betas[t * NN + n] = bnew;
    if (n == 0) outs[t] = out;
    beta = bnew;
}

__global__ __launch_bounds__(512, 2) void deerskin(
    const float* __restrict__ Xr, const float* __restrict__ Xi,
    const float* __restrict__ Tg,
    const float* __restrict__ W0r, const float* __restrict__ W0i,
    const float* __restrict__ Phi0, const float* __restrict__ Beta0,
    float* __restrict__ outs, float* __restrict__ betas, float* __restrict__ gammas)
{
    __shared__ __align__(16) float sP[16];   // double-buffered 8 wave-partials
    const int n = threadIdx.x;
    const int lane = n & 63;
    const int wid = n >> 6;

    // Per-neuron W row in registers as d-pair float2s.
    v2f wr[DP], wi[DP];
    {
        const v2f* wr0 = (const v2f*)(W0r + n * DD);
        const v2f* wi0 = (const v2f*)(W0i + n * DD);
#pragma unroll
        for (int j = 0; j < DP; ++j) { wr[j] = wr0[j]; wi[j] = wi0[j]; }
    }
    float phi = Phi0[n];
    float beta = Beta0[n];
    float lt = 0.0f;
    float err = 0.0f;

    // x double-buffer in registers; 2x-unrolled loop swaps roles (no copies).
    v2f xa_r[DP], xa_i[DP], xb_r[DP], xb_i[DP];
    float tgtA = Tg[0], tgtB;
    {
        const v2f* pr = (const v2f*)Xr;
        const v2f* pi_ = (const v2f*)Xi;
#pragma unroll
        for (int j = 0; j < DP; ++j) { xa_r[j] = pr[j]; xa_i[j] = pi_[j]; }
    }

    for (int t = 0; t < TT; t += 2) {
        do_step(t,     Xr, Xi, Tg, wr, wi, xa_r, xa_i, xb_r, xb_i, tgtA, tgtB,
                phi, beta, lt, err, outs, betas, gammas, sP, n, lane, wid);
        do_step(t + 1, Xr, Xi, Tg, wr, wi, xb_r, xb_i, xa_r, xa_i, tgtB, tgtA,
                phi, beta, lt, err, outs, betas, gammas, sP, n, lane, wid);
    }
}

extern "C" void kernel_launch(void* const* d_in, const int* in_sizes, int n_in,
                              void* d_out, int out_size, void* d_ws, size_t ws_size,
                              hipStream_t stream) {
    const float* Xr    = (const float*)d_in[0];   // [T, D]
    const float* Xi    = (const float*)d_in[1];   // [T, D]
    const float* Tg    = (const float*)d_in[2];   // [T]
    const float* W0r   = (const float*)d_in[3];   // [N, D]
    const float* W0i   = (const float*)d_in[4];   // [N, D]
    const float* Phi0  = (const float*)d_in[5];   // [N]
    const float* Beta0 = (const float*)d_in[6];   // [N]

    float* outs   = (float*)d_out;                // [T]
    float* betas  = outs + TT;                    // [T, N]
    float* gammas = betas + (size_t)TT * NN;      // [T, N]

    deerskin<<<1, NN, 0, stream>>>(Xr, Xi, Tg, W0r, W0i, Phi0, Beta0,
                                   outs, betas, gammas);
}

// Round 6
// 9200.008 us; speedup vs baseline: 1.5759x; 1.3662x over previous
//
#include <hip/hip_runtime.h>

#define NN 512
#define DD 32
#define TT 8192

typedef float v4f __attribute__((ext_vector_type(4)));
typedef __attribute__((address_space(3))) float lds_f;
typedef __attribute__((address_space(3))) void lds_v;
typedef const __attribute__((address_space(1))) void glb_v;

constexpr float F_OMEGA = 10.0f;
constexpr float F_DT = 1e-3f;
constexpr float F_TWO_PI = 6.28318530717958647692f;
constexpr float F_INV_TWO_PI = 0.15915494309189533577f;

// Barrier waiting LDS/SMEM only (lgkmcnt), never vmcnt: glds prefetches and
// output stores stay in flight across the per-step sync.
__device__ __forceinline__ void barrier_lgkm() {
    asm volatile("s_waitcnt lgkmcnt(0)\n\ts_barrier" ::: "memory");
}

// Async global->LDS stage, vmcnt-tracked. Wave-uniform LDS base + lane*4.
__device__ __forceinline__ void glds4(const float* g, lds_f* dst) {
    __builtin_amdgcn_global_load_lds((glb_v*)g, (lds_v*)dst, 4, 0, 0);
}

// Asm-laundered LDS reads: compiler cannot scalarize them, cannot hoist uses
// above the tied lgkm wait, and does not know they alias the glds buffers
// (so it cannot insert a conservative vmcnt(0) drain).
#define DSR128(dst, addr, off) \
    asm volatile("ds_read_b128 %0, %1 offset:" #off : "=v"(dst) : "v"(addr))
#define DSR32(dst, addr, off) \
    asm volatile("ds_read_b32 %0, %1 offset:" #off : "=v"(dst) : "v"(addr))

// One step of a DPP-based wave64 reduction: x += dpp_move(x).
#define DPP_ADD(x, ctrl, rmask)                                                 \
    {                                                                           \
        int _t = __builtin_amdgcn_update_dpp(0, __float_as_int(x),              \
                                             (ctrl), (rmask), 0xf, true);       \
        (x) += __int_as_float(_t);                                              \
    }

__device__ __forceinline__ float wave_reduce_to_lane63(float x) {
    DPP_ADD(x, 0xB1, 0xf);   // + xor1
    DPP_ADD(x, 0x4E, 0xf);   // + xor2
    DPP_ADD(x, 0x141, 0xf);  // + xor4
    DPP_ADD(x, 0x140, 0xf);  // + xor8
    DPP_ADD(x, 0x142, 0xa);  // row_bcast15
    DPP_ADD(x, 0x143, 0xc);  // row_bcast31
    return x;                // lane 63 = full wave sum
}

__device__ __forceinline__ float hsum4(v4f a) {
    return (a.x + a.y) + (a.z + a.w);
}

__global__ __launch_bounds__(512, 2) void deerskin(
    const float* __restrict__ Xr, const float* __restrict__ Xi,
    const float* __restrict__ Tg,
    const float* __restrict__ W0r, const float* __restrict__ W0i,
    const float* __restrict__ Phi0, const float* __restrict__ Beta0,
    float* __restrict__ outs, float* __restrict__ betas, float* __restrict__ gammas)
{
    // 3 x-staging buffers (72 floats = 288B each: [0..31]=xr, [32..63]=xi,
    // [64]=tgt) + 16-float double-buffered partial array.
    __shared__ __align__(16) float xbuf[3][72];
    __shared__ __align__(16) float sP[16];

    const int n = threadIdx.x;
    const int lane = n & 63;
    const int wid = n >> 6;

    // W row in registers as v4f[8] (64 VGPRs per re/im).
    v4f wr4[8], wi4[8];
    {
        const v4f* wr0 = (const v4f*)(W0r + n * DD);
        const v4f* wi0 = (const v4f*)(W0i + n * DD);
#pragma unroll
        for (int j = 0; j < 8; ++j) { wr4[j] = wr0[j]; wi4[j] = wi0[j]; }
    }
    float phi = Phi0[n];
    float beta = Beta0[n];
    float lt = 0.0f;
    float err = 0.0f;

    // Per-lane glds source: lanes 0..31 cover the Xr row, 32..63 the Xi row.
    const float* xsrc = ((lane < 32) ? Xr : Xi) + (lane & 31);

    lds_f* pcur = (lds_f*)&xbuf[0][0];
    lds_f* pnxt = (lds_f*)&xbuf[1][0];
    lds_f* pfut = (lds_f*)&xbuf[2][0];

    // ---- prologue: stage x(0) -> buf0, x(1) -> buf1; wave 0 drains, all sync.
    if (wid == 0) {
        glds4(xsrc, pcur);
        glds4(xsrc + DD, pnxt);
        if (lane == 0) {
            glds4(Tg, pcur + 64);
            glds4(Tg + 1, pnxt + 64);
        }
        asm volatile("s_waitcnt vmcnt(0)" ::: "memory");
    }
    barrier_lgkm();

    for (int t = 0; t < TT; ++t) {
        // ---- 1. stage x(t+2) into the future buffer (wave 0; vmcnt-tracked,
        // drained only by the counted wait 2 steps of slack later).
        if (wid == 0) {
            int tf = t + 2; tf = (tf < TT) ? tf : (TT - 1);
            glds4(xsrc + (size_t)tf * DD, pfut);
            if (lane == 0) glds4(Tg + tf, pfut + 64);
        }

        // ---- 2. x-independent precompute (fills staging latency) ----
        const float gamma = __expf(-0.5f * beta);
        const float dtl = gamma * F_DT;
        lt += dtl;
        const float theta = fmaf(F_OMEGA, lt, phi);
        float rev = theta * F_INV_TWO_PI;
        rev -= floorf(rev);
        const float s = __builtin_amdgcn_sinf(rev);
        const float c = __builtin_amdgcn_cosf(rev);
        const float a_sA = 1.0f - __expf(-2.0f * F_DT * (gamma + 1e-6f));
        const float a_sB = 1.0f - __expf(-F_DT / 0.03f);

        // ---- 3. x(t) from LDS via laundered ds_read + tied lgkm wait ----
        const unsigned lcur = (unsigned)(unsigned long long)pcur;
        v4f cr[8], ci[8];
        float tgt;
        DSR128(cr[0], lcur, 0);   DSR128(cr[1], lcur, 16);
        DSR128(cr[2], lcur, 32);  DSR128(cr[3], lcur, 48);
        DSR128(cr[4], lcur, 64);  DSR128(cr[5], lcur, 80);
        DSR128(cr[6], lcur, 96);  DSR128(cr[7], lcur, 112);
        DSR128(ci[0], lcur, 128); DSR128(ci[1], lcur, 144);
        DSR128(ci[2], lcur, 160); DSR128(ci[3], lcur, 176);
        DSR128(ci[4], lcur, 192); DSR128(ci[5], lcur, 208);
        DSR128(ci[6], lcur, 224); DSR128(ci[7], lcur, 240);
        DSR32(tgt, lcur, 256);
        asm volatile("s_waitcnt lgkmcnt(0)"
            : "+v"(cr[0]), "+v"(cr[1]), "+v"(cr[2]), "+v"(cr[3]),
              "+v"(cr[4]), "+v"(cr[5]), "+v"(cr[6]), "+v"(cr[7]),
              "+v"(ci[0]), "+v"(ci[1]), "+v"(ci[2]), "+v"(ci[3]),
              "+v"(ci[4]), "+v"(ci[5]), "+v"(ci[6]), "+v"(ci[7]),
              "+v"(tgt) :: "memory");

        // ---- 4. Z = W @ x, 4 packed v4f accumulator chains ----
        v4f Arr = {0,0,0,0}, Aii = {0,0,0,0}, Ari = {0,0,0,0}, Air = {0,0,0,0};
#pragma unroll
        for (int j = 0; j < 8; ++j) {
            Arr += wr4[j] * cr[j];
            Aii += wi4[j] * ci[j];
            Ari += wr4[j] * ci[j];
            Air += wi4[j] * cr[j];
        }
        const float zr = hsum4(Arr) - hsum4(Aii);
        const float zi = hsum4(Ari) + hsum4(Air);

        // Y = |Z| * relu(cos(theta - angle(Z))) == relu(zr*cos + zi*sin)
        const float Y = fmaxf(fmaf(zr, c, zi * s), 0.0f);

        // ---- 5. reduce 512 -> 1: DPP wave sum, 8 partials via LDS ----
        float v = wave_reduce_to_lane63(Y * c);
        if (lane == 63) sP[((t & 1) << 3) + wid] = v;

        // ---- 6. out-independent precompute (off the post-barrier path) ----
        const float inv_t = 1.0f / (fabsf(tgt) + 0.01f);
        const float yy = Y * Y;
        const float g = 0.05f * Y * dtl;
        phi += (2.0f / (float)NN) * (-tgt * s) * dtl;
        phi = phi - F_TWO_PI * floorf(phi * F_INV_TWO_PI);

        // ---- 7. counted drain of glds(t+1) (wave 0), then sync ----
        // Outstanding newer than glds(t+1): glds(t+2) x2 + stores(t-1) x3 = 5.
        if (wid == 0) asm volatile("s_waitcnt vmcnt(5)" ::: "memory");
        barrier_lgkm();

        // ---- 8. out + short scalar feedback chain ----
        const float4* sp4 = (const float4*)(sP + ((t & 1) << 3));
        const float4 p0 = sp4[0], p1 = sp4[1];
        const float out = ((p0.x + p0.y) + (p0.z + p0.w)) +
                          ((p1.x + p1.y) + (p1.z + p1.w));

        const float raw = fabsf(tgt - out);
        err = 0.99f * err + 0.01f * raw;
        const float rel = err * inv_t;
        const float btg = 3.5f * __expf(-5.0f * rel);
        const float a_s = (btg > beta) ? a_sA : a_sB;
        float bnew = beta + a_s * (btg - beta);
        bnew = fminf(fmaxf(bnew, 0.005f), 5.0f);

        // ---- 9. W = W*(1 - (bnew*yy)*dtl) + g*x (packed, same FP order) ----
        const float k = (bnew * yy) * dtl;
        const float m1 = 1.0f - k;
        const v4f m1v = {m1, m1, m1, m1};
        const v4f gv = {g, g, g, g};
#pragma unroll
        for (int j = 0; j < 8; ++j) {
            wr4[j] = wr4[j] * m1v + gv * cr[j];
            wi4[j] = wi4[j] * m1v + gv * ci[j];
        }

        // ---- 10. outputs: exactly 3 VMEM stores per wave per step (outs via
        // lane 63 of EVERY wave -> identical value, uniform vmcnt count) ----
        gammas[t * NN + n] = gamma;   // gamma from OLD beta, per reference
        betas[t * NN + n] = bnew;
        if (lane == 63) outs[t] = out;
        beta = bnew;

        // ---- 11. rotate staging buffers ----
        lds_f* tmp = pcur; pcur = pnxt; pnxt = pfut; pfut = tmp;
    }
}

extern "C" void kernel_launch(void* const* d_in, const int* in_sizes, int n_in,
                              void* d_out, int out_size, void* d_ws, size_t ws_size,
                              hipStream_t stream) {
    const float* Xr    = (const float*)d_in[0];   // [T, D]
    const float* Xi    = (const float*)d_in[1];   // [T, D]
    const float* Tg    = (const float*)d_in[2];   // [T]
    const float* W0r   = (const float*)d_in[3];   // [N, D]
    const float* W0i   = (const float*)d_in[4];   // [N, D]
    const float* Phi0  = (const float*)d_in[5];   // [N]
    const float* Beta0 = (const float*)d_in[6];   // [N]

    float* outs   = (float*)d_out;                // [T]
    float* betas  = outs + TT;                    // [T, N]
    float* gammas = betas + (size_t)TT * NN;      // [T, N]

    deerskin<<<1, NN, 0, stream>>>(Xr, Xi, Tg, W0r, W0i, Phi0, Beta0,
                                   outs, betas, gammas);
}